// Round 2
// baseline (42.945 us; speedup 1.0000x reference)
//
#include <hip/hip_runtime.h>

// ConvSurface: out[m,f,k] = max_s relu( (point_{m,f,s} - center_{m,f}) . W_k + b_k )
//   point = alpha*c1 + beta*c2 + gamma*c3  over 24 samples (8 per neighbor, n = s%3)
// Restructured: per lane k, precompute d_i = c_i.W_k per neighbor; using
// alpha+beta+gamma==1:  p.W = d1 + beta*(d2-d1) + gamma*(d3-d1).
// Bias/center-dot/relu folded out of the max (monotone).

#define NM 8
#define NF 16384
#define NK 64

__global__ __launch_bounds__(256) void conv_surface_kernel(
    const float* __restrict__ centers,   // [M,F,3]
    const float* __restrict__ nc,        // [M,F,3,3,3]
    const float* __restrict__ beta,      // [F,24]
    const float* __restrict__ gammav,    // [F,24]
    const float* __restrict__ W,         // [64,3]
    const float* __restrict__ b,         // [64]
    float* __restrict__ out)             // [M,F,64]
{
    const int lane = threadIdx.x & 63;
    // force wave id into SGPR so all face-level addresses are provably uniform
    const int wav  = __builtin_amdgcn_readfirstlane((int)(threadIdx.x >> 6));
    const int gidx = blockIdx.x * 4 + wav;        // flat m*NF + f
    const int f    = gidx & (NF - 1);

    // per-lane kernel weights (64x3, stride-3 reads; tiny, L1-resident)
    const float w0 = W[lane * 3 + 0];
    const float w1 = W[lane * 3 + 1];
    const float w2 = W[lane * 3 + 2];
    const float bk = b[lane];

    const float* __restrict__ cp = centers + (size_t)gidx * 3;
    const float cdot = cp[0] * w0 + cp[1] * w1 + cp[2] * w2;

    // 27 wave-uniform floats: 3 neighbors x 3 corners x xyz
    const float* __restrict__ tp = nc + (size_t)gidx * 27;
    float d1[3], e2[3], e3[3];
#pragma unroll
    for (int n = 0; n < 3; ++n) {
        const float* __restrict__ t = tp + n * 9;
        const float a1 = t[0] * w0 + t[1] * w1 + t[2] * w2;
        const float a2 = t[3] * w0 + t[4] * w1 + t[5] * w2;
        const float a3 = t[6] * w0 + t[7] * w1 + t[8] * w2;
        d1[n] = a1;
        e2[n] = a2 - a1;
        e3[n] = a3 - a1;
    }

    const float* __restrict__ bp = beta   + (size_t)f * 24;
    const float* __restrict__ gp = gammav + (size_t)f * 24;

    float mx = -3.4e38f;
#pragma unroll
    for (int s = 0; s < 24; ++s) {
        const int n = s - (s / 3) * 3;   // compile-time after unroll
        const float v = fmaf(bp[s], e2[n], fmaf(gp[s], e3[n], d1[n]));
        mx = fmaxf(mx, v);
    }

    out[(size_t)gidx * NK + lane] = fmaxf(mx - cdot + bk, 0.0f);
}

extern "C" void kernel_launch(void* const* d_in, const int* in_sizes, int n_in,
                              void* d_out, int out_size, void* d_ws, size_t ws_size,
                              hipStream_t stream) {
    const float* centers = (const float*)d_in[0];
    // d_in[1] = ring_n  (unused by the reference math)
    const float* nc      = (const float*)d_in[2];
    // d_in[3] = alpha   (unused: alpha = 1 - beta - gamma)
    const float* beta    = (const float*)d_in[4];
    const float* gammav  = (const float*)d_in[5];
    const float* W       = (const float*)d_in[6];
    const float* b       = (const float*)d_in[7];
    float* out = (float*)d_out;

    dim3 grid(NM * NF / 4), block(256);
    hipLaunchKernelGGL(conv_surface_kernel, grid, block, 0, stream,
                       centers, nc, beta, gammav, W, b, out);
}

// Round 3
// 36.658 us; speedup vs baseline: 1.1715x; 1.1715x over previous
//
#include <hip/hip_runtime.h>

// ConvSurface: out[m,f,k] = max_s relu( (point_{m,f,s} - center_{m,f}) . W_k + b_k )
// Lane = kernel k (64 = wave64). One wave per FACE, looping over the 8 meshes:
// the 48 wave-uniform beta/gamma coefficients are loaded once per face and
// reused for all 8 meshes; per-mesh loads are just center(3)+corners(27).
// Algebra: alpha+beta+gamma==1  =>  p.W = a1 + beta*(a2-a1) + gamma*(a3-a1);
// bias/center-dot/relu folded outside the sample max (monotone).

#define NM 8
#define NF 16384
#define NK 64

__global__ __launch_bounds__(256) void conv_surface_kernel(
    const float* __restrict__ centers,   // [M,F,3]
    const float* __restrict__ nc,        // [M,F,3,3,3]
    const float* __restrict__ beta,      // [F,24]
    const float* __restrict__ gammav,    // [F,24]
    const float* __restrict__ W,         // [64,3]
    const float* __restrict__ b,         // [64]
    float* __restrict__ out)             // [M,F,64]
{
    const int lane = threadIdx.x & 63;
    // wave id into SGPR so all face-level addresses are provably uniform
    const int wav  = __builtin_amdgcn_readfirstlane((int)(threadIdx.x >> 6));
    const int f    = blockIdx.x * 4 + wav;          // face id

    // per-lane kernel weights (tiny, L1-resident)
    const float w0 = W[lane * 3 + 0];
    const float w1 = W[lane * 3 + 1];
    const float w2 = W[lane * 3 + 2];
    const float bk = b[lane];

    // face sample coefficients: wave-uniform, loaded ONCE, live across m-loop
    const float* __restrict__ bp = beta   + (size_t)f * 24;
    const float* __restrict__ gp = gammav + (size_t)f * 24;
    float bs[24], gs[24];
#pragma unroll
    for (int s = 0; s < 24; ++s) { bs[s] = bp[s]; gs[s] = gp[s]; }

#pragma unroll 2
    for (int m = 0; m < NM; ++m) {
        const size_t gidx = (size_t)m * NF + f;

        const float* __restrict__ cp = centers + gidx * 3;
        const float cdot = cp[0] * w0 + cp[1] * w1 + cp[2] * w2;

        const float* __restrict__ tp = nc + gidx * 27;
        float mx = -3.4e38f;
#pragma unroll
        for (int n = 0; n < 3; ++n) {
            const float* __restrict__ t = tp + n * 9;
            const float a1 = t[0] * w0 + t[1] * w1 + t[2] * w2;
            const float a2 = t[3] * w0 + t[4] * w1 + t[5] * w2;
            const float a3 = t[6] * w0 + t[7] * w1 + t[8] * w2;
            const float e2 = a2 - a1;
            const float e3 = a3 - a1;

            // 8 samples of this neighbor: independent FMAs, balanced max tree
            float v[8];
#pragma unroll
            for (int j = 0; j < 8; ++j) {
                const int s = n + 3 * j;              // reference order: n = s%3
                v[j] = fmaf(bs[s], e2, fmaf(gs[s], e3, a1));
            }
            const float m0 = fmaxf(fmaxf(v[0], v[1]), fmaxf(v[2], v[3]));
            const float m1 = fmaxf(fmaxf(v[4], v[5]), fmaxf(v[6], v[7]));
            mx = fmaxf(mx, fmaxf(m0, m1));
        }

        out[gidx * NK + lane] = fmaxf(mx - cdot + bk, 0.0f);
    }
}

extern "C" void kernel_launch(void* const* d_in, const int* in_sizes, int n_in,
                              void* d_out, int out_size, void* d_ws, size_t ws_size,
                              hipStream_t stream) {
    const float* centers = (const float*)d_in[0];
    // d_in[1] = ring_n  (unused by the reference math)
    const float* nc      = (const float*)d_in[2];
    // d_in[3] = alpha   (unused: alpha = 1 - beta - gamma)
    const float* beta    = (const float*)d_in[4];
    const float* gammav  = (const float*)d_in[5];
    const float* W       = (const float*)d_in[6];
    const float* b       = (const float*)d_in[7];
    float* out = (float*)d_out;

    dim3 grid(NF / 4), block(256);   // one wave per face, 8 meshes per wave
    hipLaunchKernelGGL(conv_surface_kernel, grid, block, 0, stream,
                       centers, nc, beta, gammav, W, b, out);
}

// Round 4
// 31.818 us; speedup vs baseline: 1.3497x; 1.1521x over previous
//
#include <hip/hip_runtime.h>

// ConvSurface: out[m,f,k] = max_s relu( (point_{m,f,s} - center_{m,f}) . W_k + b_k )
// Lane = kernel k (64 = wave64). One wave per FACE, looping over the 8 meshes.
// Algebra: alpha+beta+gamma==1  =>  p.W = a1 + beta*(a2-a1) + gamma*(a3-a1);
// bias/center-dot/relu folded outside the sample max (monotone).
// R4: __launch_bounds__(256,4) to lift the 20-VGPR straitjacket (ILP), mesh
// loop unrolled x4 (deeper s_load pipelining), beta/gamma via float4 vector
// broadcast loads (frees SGPRs for corner prefetch).

#define NM 8
#define NF 16384
#define NK 64

__global__ __launch_bounds__(256, 4) void conv_surface_kernel(
    const float* __restrict__ centers,   // [M,F,3]
    const float* __restrict__ nc,        // [M,F,3,3,3]
    const float* __restrict__ beta,      // [F,24]
    const float* __restrict__ gammav,    // [F,24]
    const float* __restrict__ W,         // [64,3]
    const float* __restrict__ b,         // [64]
    float* __restrict__ out)             // [M,F,64]
{
    const int lane = threadIdx.x & 63;
    // wave id into SGPR so all face-level addresses are provably uniform
    const int wav  = __builtin_amdgcn_readfirstlane((int)(threadIdx.x >> 6));
    const int f    = blockIdx.x * 4 + wav;          // face id

    // per-lane kernel weights (tiny, L1-resident)
    const float w0 = W[lane * 3 + 0];
    const float w1 = W[lane * 3 + 1];
    const float w2 = W[lane * 3 + 2];
    const float bk = b[lane];

    // face sample coefficients: wave-uniform, loaded ONCE via vector float4
    // broadcasts (96B rows are 16B-aligned), live in VGPRs across the m-loop
    const float4* __restrict__ bp4 = (const float4*)(beta   + (size_t)f * 24);
    const float4* __restrict__ gp4 = (const float4*)(gammav + (size_t)f * 24);
    float bs[24], gs[24];
#pragma unroll
    for (int q = 0; q < 6; ++q) {
        const float4 bv = bp4[q];
        const float4 gv = gp4[q];
        bs[q * 4 + 0] = bv.x; bs[q * 4 + 1] = bv.y; bs[q * 4 + 2] = bv.z; bs[q * 4 + 3] = bv.w;
        gs[q * 4 + 0] = gv.x; gs[q * 4 + 1] = gv.y; gs[q * 4 + 2] = gv.z; gs[q * 4 + 3] = gv.w;
    }

#pragma unroll 4
    for (int m = 0; m < NM; ++m) {
        const size_t gidx = (size_t)m * NF + f;

        const float* __restrict__ cp = centers + gidx * 3;
        const float cdot = cp[0] * w0 + cp[1] * w1 + cp[2] * w2;

        const float* __restrict__ tp = nc + gidx * 27;
        float nmax[3];
#pragma unroll
        for (int n = 0; n < 3; ++n) {
            const float* __restrict__ t = tp + n * 9;
            const float a1 = t[0] * w0 + t[1] * w1 + t[2] * w2;
            const float a2 = t[3] * w0 + t[4] * w1 + t[5] * w2;
            const float a3 = t[6] * w0 + t[7] * w1 + t[8] * w2;
            const float e2 = a2 - a1;
            const float e3 = a3 - a1;

            // 8 samples of this neighbor: independent FMAs, max3-friendly tree
            float v[8];
#pragma unroll
            for (int j = 0; j < 8; ++j) {
                const int s = n + 3 * j;              // reference order: n = s%3
                v[j] = fmaf(bs[s], e2, fmaf(gs[s], e3, a1));
            }
            const float m0 = fmaxf(fmaxf(v[0], v[1]), v[2]);
            const float m1 = fmaxf(fmaxf(v[3], v[4]), v[5]);
            const float m2 = fmaxf(fmaxf(v[6], v[7]), m0);
            nmax[n] = fmaxf(m1, m2);
        }
        const float mx = fmaxf(fmaxf(nmax[0], nmax[1]), nmax[2]);

        out[gidx * NK + lane] = fmaxf(mx - cdot + bk, 0.0f);
    }
}

extern "C" void kernel_launch(void* const* d_in, const int* in_sizes, int n_in,
                              void* d_out, int out_size, void* d_ws, size_t ws_size,
                              hipStream_t stream) {
    const float* centers = (const float*)d_in[0];
    // d_in[1] = ring_n  (unused by the reference math)
    const float* nc      = (const float*)d_in[2];
    // d_in[3] = alpha   (unused: alpha = 1 - beta - gamma)
    const float* beta    = (const float*)d_in[4];
    const float* gammav  = (const float*)d_in[5];
    const float* W       = (const float*)d_in[6];
    const float* b       = (const float*)d_in[7];
    float* out = (float*)d_out;

    dim3 grid(NF / 4), block(256);   // one wave per face, 8 meshes per wave
    hipLaunchKernelGGL(conv_surface_kernel, grid, block, 0, stream,
                       centers, nc, beta, gammav, W, b, out);
}